// Round 5
// baseline (70.050 us; speedup 1.0000x reference)
//
#include <hip/hip_runtime.h>

#define NUM_BINS 256
#define PLANES 48                     // B*C = 16*3
#define PLANE_ELEMS (512 * 512)       // H*W
#define BPP 16                        // blocks per plane
#define THREADS 256
#define F4_PER_BLOCK (PLANE_ELEMS / 4 / BPP)   // 4096 float4 per block
#define NITER (F4_PER_BLOCK / (2 * THREADS))   // 8 iters x 2 float4/thread

__global__ __launch_bounds__(THREADS) void hist_kernel(const float* __restrict__ pred,
                                                       const float* __restrict__ target,
                                                       unsigned* __restrict__ hist,
                                                       unsigned* __restrict__ totals) {
    const int t = threadIdx.x;
    const int lane = t & 63;

    const int gid   = blockIdx.x;
    const int which = gid / (PLANES * BPP);
    const int rem   = gid - which * (PLANES * BPP);
    const int plane = rem / BPP;
    const int cblk  = rem - plane * BPP;

    const float* src = which ? target : pred;
    const float4* p = reinterpret_cast<const float4*>(src + (size_t)plane * PLANE_ELEMS)
                      + (size_t)cblk * F4_PER_BLOCK;

    // per-lane broadcast masks: mk = (lane bit k set) ? 0 : ~0  -> term = Bk ^ mk
    const unsigned m0 = ((lane >> 0) & 1) ? 0u : ~0u;
    const unsigned m1 = ((lane >> 1) & 1) ? 0u : ~0u;
    const unsigned m2 = ((lane >> 2) & 1) ? 0u : ~0u;
    const unsigned m3 = ((lane >> 3) & 1) ? 0u : ~0u;
    const unsigned m4 = ((lane >> 4) & 1) ? 0u : ~0u;
    const unsigned m5 = ((lane >> 5) & 1) ? 0u : ~0u;

    unsigned c0 = 0, c1 = 0, c2 = 0, c3 = 0;   // counts for bins lane+0/64/128/192
    unsigned tot = 0;                           // wave-uniform in-range count

#define ROUND(xx)                                                                 \
    do {                                                                          \
        float x = (xx);                                                           \
        int b = (int)(x * 256.0f);            /* trunc == floor for x >= 0 */     \
        b = b > 255 ? 255 : b;                /* x == 1.0 -> last bin */          \
        unsigned long long V = __ballot((x >= 0.0f) && (x <= 1.0f));              \
        unsigned long long B0 = __ballot(b & 1);                                  \
        unsigned long long B1 = __ballot(b & 2);                                  \
        unsigned long long B2 = __ballot(b & 4);                                  \
        unsigned long long B3 = __ballot(b & 8);                                  \
        unsigned long long B4 = __ballot(b & 16);                                 \
        unsigned long long B5 = __ballot(b & 32);                                 \
        int q = b >> 6;                                                           \
        unsigned long long T0 = __ballot(q == 0) & V;                             \
        unsigned long long T1 = __ballot(q == 1) & V;                             \
        unsigned long long T2 = __ballot(q == 2) & V;                             \
        unsigned long long T3 = __ballot(q == 3) & V;                             \
        unsigned lo = ((unsigned)B0 ^ m0) & ((unsigned)B1 ^ m1) &                 \
                      ((unsigned)B2 ^ m2) & ((unsigned)B3 ^ m3) &                 \
                      ((unsigned)B4 ^ m4) & ((unsigned)B5 ^ m5);                  \
        unsigned hi = ((unsigned)(B0 >> 32) ^ m0) & ((unsigned)(B1 >> 32) ^ m1) & \
                      ((unsigned)(B2 >> 32) ^ m2) & ((unsigned)(B3 >> 32) ^ m3) & \
                      ((unsigned)(B4 >> 32) ^ m4) & ((unsigned)(B5 >> 32) ^ m5);  \
        c0 += __popc(lo & (unsigned)T0) + __popc(hi & (unsigned)(T0 >> 32));      \
        c1 += __popc(lo & (unsigned)T1) + __popc(hi & (unsigned)(T1 >> 32));      \
        c2 += __popc(lo & (unsigned)T2) + __popc(hi & (unsigned)(T2 >> 32));      \
        c3 += __popc(lo & (unsigned)T3) + __popc(hi & (unsigned)(T3 >> 32));      \
        tot += (unsigned)__popcll(V);                                             \
    } while (0)

    for (int i = 0; i < NITER; ++i) {
        float4 va = p[i * 2 * THREADS + t];
        float4 vb = p[i * 2 * THREADS + THREADS + t];
        ROUND(va.x); ROUND(va.y); ROUND(va.z); ROUND(va.w);
        ROUND(vb.x); ROUND(vb.y); ROUND(vb.z); ROUND(vb.w);
    }
#undef ROUND

    unsigned* gh = hist + (size_t)(which * PLANES + plane) * NUM_BINS;
    atomicAdd(&gh[lane], c0);
    atomicAdd(&gh[lane + 64], c1);
    atomicAdd(&gh[lane + 128], c2);
    atomicAdd(&gh[lane + 192], c3);
    if (lane == 0) atomicAdd(&totals[which * PLANES + plane], tot);
}

__global__ __launch_bounds__(1024) void loss_kernel(const unsigned* __restrict__ hist,
                                                    const unsigned* __restrict__ totals,
                                                    float* __restrict__ out) {
    __shared__ double inv[2 * PLANES];
    __shared__ double sd[16];
    const int t = threadIdx.x;
    if (t < 2 * PLANES) inv[t] = 1.0 / ((double)totals[t] + 1e-8);
    __syncthreads();

    const uint4* h4 = reinterpret_cast<const uint4*>(hist);
    double acc = 0.0;
    for (int i = t; i < (PLANES * NUM_BINS) / 4; i += 1024) {
        uint4 hp = h4[i];
        uint4 ht = h4[i + (PLANES * NUM_BINS) / 4];
        const double ip = inv[i >> 6];
        const double it = inv[PLANES + (i >> 6)];
        double d0 = (double)hp.x * ip - (double)ht.x * it;
        double d1 = (double)hp.y * ip - (double)ht.y * it;
        double d2 = (double)hp.z * ip - (double)ht.z * it;
        double d3 = (double)hp.w * ip - (double)ht.w * it;
        acc += d0 * d0 + d1 * d1 + d2 * d2 + d3 * d3;
    }
    for (int off = 32; off; off >>= 1) acc += __shfl_down(acc, off, 64);
    if ((t & 63) == 0) sd[t >> 6] = acc;
    __syncthreads();
    if (t == 0) {
        double s = 0.0;
        for (int w = 0; w < 16; ++w) s += sd[w];
        out[0] = (float)(s / (double)(PLANES * NUM_BINS));
    }
}

extern "C" void kernel_launch(void* const* d_in, const int* in_sizes, int n_in,
                              void* d_out, int out_size, void* d_ws, size_t ws_size,
                              hipStream_t stream) {
    const float* pred   = (const float*)d_in[0];
    const float* target = (const float*)d_in[1];
    float* out = (float*)d_out;
    unsigned* hist   = (unsigned*)d_ws;                          // [2][48][256] u32
    unsigned* totals = hist + (size_t)2 * PLANES * NUM_BINS;     // [96] u32

    hipMemsetAsync(d_ws, 0, ((size_t)2 * PLANES * NUM_BINS + 2 * PLANES) * sizeof(unsigned), stream);
    hist_kernel<<<2 * PLANES * BPP, THREADS, 0, stream>>>(pred, target, hist, totals);
    loss_kernel<<<1, 1024, 0, stream>>>(hist, totals, out);
}

// Round 6
// 55.804 us; speedup vs baseline: 1.2553x; 1.2553x over previous
//
#include <hip/hip_runtime.h>

#define NUM_BINS 256
#define PLANES 48                     // B*C = 16*3
#define PLANE_ELEMS (512 * 512)       // H*W
#define BPP 16                        // blocks per plane per input
#define THREADS 256                   // 4 waves: waves 0-2 ballot, wave 3 LDS-atomic
#define F4_PER_BLOCK (PLANE_ELEMS / 4 / BPP)   // 4096 float4
#define BAL_F4 640                    // float4 per ballot wave (10 per lane)
#define ATM_F4 (F4_PER_BLOCK - 3 * BAL_F4)     // 2176 float4 (34 per lane)
#define NSUB 16                       // sub-histograms for the atomic wave
#define HSTRIDE 257                   // +1 pad

__global__ __launch_bounds__(THREADS) void hist_kernel(const float* __restrict__ pred,
                                                       const float* __restrict__ target,
                                                       unsigned* __restrict__ hist,
                                                       unsigned* __restrict__ totals) {
    __shared__ unsigned lh[NSUB * HSTRIDE];   // used ONLY by wave 3 (wave-private)
    const int t = threadIdx.x;
    const int lane = t & 63;
    const int w = t >> 6;

    const int gid   = blockIdx.x;
    const int which = gid / (PLANES * BPP);
    const int rem   = gid - which * (PLANES * BPP);
    const int plane = rem / BPP;
    const int cblk  = rem - plane * BPP;

    const float* src = which ? target : pred;
    const float4* p = reinterpret_cast<const float4*>(src + (size_t)plane * PLANE_ELEMS)
                      + (size_t)cblk * F4_PER_BLOCK;
    unsigned* gh = hist + (size_t)(which * PLANES + plane) * NUM_BINS;
    unsigned* tp = &totals[which * PLANES + plane];

    if (w == 3) {
        // ---------------- LDS-atomic wave (DS pipe) ----------------
        for (int i = lane; i < NSUB * HSTRIDE; i += 64) lh[i] = 0u;
        asm volatile("s_waitcnt lgkmcnt(0)");   // zeroing complete before atomics

        unsigned* sub = lh + (size_t)(lane & (NSUB - 1)) * HSTRIDE;
        const float4* q = p + 3 * BAL_F4;
        for (int i = 0; i < ATM_F4 / 128; ++i) {   // 17 iters, 2 float4/lane each
            float4 a = q[i * 128 + lane];
            float4 b = q[i * 128 + 64 + lane];
            float e[8] = {a.x, a.y, a.z, a.w, b.x, b.y, b.z, b.w};
#pragma unroll
            for (int j = 0; j < 8; ++j) {
                float x = e[j];
                if (x >= 0.0f && x <= 1.0f) {        // out-of-range ignored
                    int bi = (int)(x * 256.0f);       // trunc == floor for x >= 0
                    bi = bi > 255 ? 255 : bi;         // x == 1.0 -> last bin
                    atomicAdd(&sub[bi], 1u);          // ds_add_u32, no return
                }
            }
        }
        asm volatile("s_waitcnt lgkmcnt(0)");   // atomics done before flush reads

        unsigned c[4] = {0u, 0u, 0u, 0u};
        for (int h = 0; h < NSUB; ++h) {
#pragma unroll
            for (int q4 = 0; q4 < 4; ++q4) c[q4] += lh[h * HSTRIDE + q4 * 64 + lane];
        }
#pragma unroll
        for (int q4 = 0; q4 < 4; ++q4)
            if (c[q4]) atomicAdd(&gh[q4 * 64 + lane], c[q4]);

        unsigned bt = c[0] + c[1] + c[2] + c[3];     // wave's in-range count
        for (int off = 32; off; off >>= 1) bt += __shfl_down(bt, off, 64);
        if (lane == 0) atomicAdd(tp, bt);
    } else {
        // ---------------- ballot waves (VALU pipe) ----------------
        const unsigned m0 = ((lane >> 0) & 1) ? 0u : ~0u;
        const unsigned m1 = ((lane >> 1) & 1) ? 0u : ~0u;
        const unsigned m2 = ((lane >> 2) & 1) ? 0u : ~0u;
        const unsigned m3 = ((lane >> 3) & 1) ? 0u : ~0u;
        const unsigned m4 = ((lane >> 4) & 1) ? 0u : ~0u;
        const unsigned m5 = ((lane >> 5) & 1) ? 0u : ~0u;

        unsigned c0 = 0, c1 = 0, c2 = 0, c3 = 0;
        unsigned tot = 0;

#define ROUND(xx)                                                                 \
    do {                                                                          \
        float x = (xx);                                                           \
        int b = (int)(x * 256.0f);                                                \
        b = b > 255 ? 255 : b;                                                    \
        unsigned long long V = __ballot((x >= 0.0f) && (x <= 1.0f));              \
        unsigned long long B0 = __ballot(b & 1);                                  \
        unsigned long long B1 = __ballot(b & 2);                                  \
        unsigned long long B2 = __ballot(b & 4);                                  \
        unsigned long long B3 = __ballot(b & 8);                                  \
        unsigned long long B4 = __ballot(b & 16);                                 \
        unsigned long long B5 = __ballot(b & 32);                                 \
        int qq = b >> 6;                                                          \
        unsigned long long T0 = __ballot(qq == 0) & V;                            \
        unsigned long long T1 = __ballot(qq == 1) & V;                            \
        unsigned long long T2 = __ballot(qq == 2) & V;                            \
        unsigned long long T3 = __ballot(qq == 3) & V;                            \
        unsigned lo = ((unsigned)B0 ^ m0) & ((unsigned)B1 ^ m1) &                 \
                      ((unsigned)B2 ^ m2) & ((unsigned)B3 ^ m3) &                 \
                      ((unsigned)B4 ^ m4) & ((unsigned)B5 ^ m5);                  \
        unsigned hi = ((unsigned)(B0 >> 32) ^ m0) & ((unsigned)(B1 >> 32) ^ m1) & \
                      ((unsigned)(B2 >> 32) ^ m2) & ((unsigned)(B3 >> 32) ^ m3) & \
                      ((unsigned)(B4 >> 32) ^ m4) & ((unsigned)(B5 >> 32) ^ m5);  \
        c0 += __popc(lo & (unsigned)T0) + __popc(hi & (unsigned)(T0 >> 32));      \
        c1 += __popc(lo & (unsigned)T1) + __popc(hi & (unsigned)(T1 >> 32));      \
        c2 += __popc(lo & (unsigned)T2) + __popc(hi & (unsigned)(T2 >> 32));      \
        c3 += __popc(lo & (unsigned)T3) + __popc(hi & (unsigned)(T3 >> 32));      \
        tot += (unsigned)__popcll(V);                                             \
    } while (0)

        const float4* pw = p + w * BAL_F4;
        for (int i = 0; i < BAL_F4 / 128; ++i) {    // 5 iters, 2 float4/lane each
            float4 va = pw[i * 128 + lane];
            float4 vb = pw[i * 128 + 64 + lane];
            ROUND(va.x); ROUND(va.y); ROUND(va.z); ROUND(va.w);
            ROUND(vb.x); ROUND(vb.y); ROUND(vb.z); ROUND(vb.w);
        }
#undef ROUND

        atomicAdd(&gh[lane], c0);
        atomicAdd(&gh[lane + 64], c1);
        atomicAdd(&gh[lane + 128], c2);
        atomicAdd(&gh[lane + 192], c3);
        if (lane == 0) atomicAdd(tp, tot);
    }
}

__global__ __launch_bounds__(1024) void loss_kernel(const unsigned* __restrict__ hist,
                                                    const unsigned* __restrict__ totals,
                                                    float* __restrict__ out) {
    __shared__ double inv[2 * PLANES];
    __shared__ double sd[16];
    const int t = threadIdx.x;
    if (t < 2 * PLANES) inv[t] = 1.0 / ((double)totals[t] + 1e-8);
    __syncthreads();

    const uint4* h4 = reinterpret_cast<const uint4*>(hist);
    double acc = 0.0;
    for (int i = t; i < (PLANES * NUM_BINS) / 4; i += 1024) {
        uint4 hp = h4[i];
        uint4 ht = h4[i + (PLANES * NUM_BINS) / 4];
        const double ip = inv[i >> 6];
        const double it = inv[PLANES + (i >> 6)];
        double d0 = (double)hp.x * ip - (double)ht.x * it;
        double d1 = (double)hp.y * ip - (double)ht.y * it;
        double d2 = (double)hp.z * ip - (double)ht.z * it;
        double d3 = (double)hp.w * ip - (double)ht.w * it;
        acc += d0 * d0 + d1 * d1 + d2 * d2 + d3 * d3;
    }
    for (int off = 32; off; off >>= 1) acc += __shfl_down(acc, off, 64);
    if ((t & 63) == 0) sd[t >> 6] = acc;
    __syncthreads();
    if (t == 0) {
        double s = 0.0;
        for (int w = 0; w < 16; ++w) s += sd[w];
        out[0] = (float)(s / (double)(PLANES * NUM_BINS));
    }
}

extern "C" void kernel_launch(void* const* d_in, const int* in_sizes, int n_in,
                              void* d_out, int out_size, void* d_ws, size_t ws_size,
                              hipStream_t stream) {
    const float* pred   = (const float*)d_in[0];
    const float* target = (const float*)d_in[1];
    float* out = (float*)d_out;
    unsigned* hist   = (unsigned*)d_ws;                          // [2][48][256] u32
    unsigned* totals = hist + (size_t)2 * PLANES * NUM_BINS;     // [96] u32

    hipMemsetAsync(d_ws, 0, ((size_t)2 * PLANES * NUM_BINS + 2 * PLANES) * sizeof(unsigned), stream);
    hist_kernel<<<2 * PLANES * BPP, THREADS, 0, stream>>>(pred, target, hist, totals);
    loss_kernel<<<1, 1024, 0, stream>>>(hist, totals, out);
}